// Round 14
// baseline (1274.038 us; speedup 1.0000x reference)
//
#include <hip/hip_runtime.h>
#include <hip/hip_bf16.h>

typedef __bf16 bf16;
typedef __bf16 bf16x8 __attribute__((ext_vector_type(8)));
typedef __bf16 bf16x4 __attribute__((ext_vector_type(4)));
typedef float f32x4 __attribute__((ext_vector_type(4)));

#define D_MODEL 2048
#define D_INNER 4096
#define ROWS    8192   // B*T

__device__ __forceinline__ void gload_lds16(const void* g, void* l) {
    __builtin_amdgcn_global_load_lds(
        (const __attribute__((address_space(1))) void*)g,
        (__attribute__((address_space(3))) void*)l, 16, 0, 0);
}

// ---------------- device bodies ----------------
__device__ __forceinline__ void f2b_body(const float* __restrict__ in,
                                         bf16* __restrict__ out, int i, int n8) {
    if (i >= n8) return;
    long base = (long)i * 8;
    float4 a = *(const float4*)(in + base);
    float4 b = *(const float4*)(in + base + 4);
    bf16x8 o;
    o[0] = (bf16)a.x; o[1] = (bf16)a.y; o[2] = (bf16)a.z; o[3] = (bf16)a.w;
    o[4] = (bf16)b.x; o[5] = (bf16)b.y; o[6] = (bf16)b.z; o[7] = (bf16)b.w;
    *(bf16x8*)(out + base) = o;
}

__device__ __forceinline__ void rmsnorm_body(const float* __restrict__ x,
                                             bf16* __restrict__ h, int row) {
    const float* xr = x + (long)row * D_MODEL;
    float4 v0 = ((const float4*)xr)[threadIdx.x * 2];
    float4 v1 = ((const float4*)xr)[threadIdx.x * 2 + 1];
    float ss = v0.x*v0.x + v0.y*v0.y + v0.z*v0.z + v0.w*v0.w
             + v1.x*v1.x + v1.y*v1.y + v1.z*v1.z + v1.w*v1.w;
    #pragma unroll
    for (int o = 32; o; o >>= 1) ss += __shfl_xor(ss, o, 64);
    __shared__ float red[4];
    if ((threadIdx.x & 63) == 0) red[threadIdx.x >> 6] = ss;
    __syncthreads();
    float tot = red[0] + red[1] + red[2] + red[3];
    float scale = 45.254834f / fmaxf(sqrtf(tot), 1e-12f);
    bf16x8 o;
    o[0] = (bf16)(v0.x*scale); o[1] = (bf16)(v0.y*scale);
    o[2] = (bf16)(v0.z*scale); o[3] = (bf16)(v0.w*scale);
    o[4] = (bf16)(v1.x*scale); o[5] = (bf16)(v1.y*scale);
    o[6] = (bf16)(v1.z*scale); o[7] = (bf16)(v1.w*scale);
    *(bf16x8*)(h + (long)row * D_MODEL + threadIdx.x * 8) = o;
}

__device__ __forceinline__ void rmsnorm_body_b16(const bf16* __restrict__ x,
                                                 bf16* __restrict__ h, int row) {
    const bf16* xr = x + (long)row * D_MODEL;
    bf16x8 v = *(const bf16x8*)(xr + threadIdx.x * 8);
    float f[8];
    float ss = 0.f;
    #pragma unroll
    for (int e = 0; e < 8; ++e) { f[e] = (float)v[e]; ss += f[e] * f[e]; }
    #pragma unroll
    for (int o = 32; o; o >>= 1) ss += __shfl_xor(ss, o, 64);
    __shared__ float red[4];
    if ((threadIdx.x & 63) == 0) red[threadIdx.x >> 6] = ss;
    __syncthreads();
    float tot = red[0] + red[1] + red[2] + red[3];
    float scale = 45.254834f / fmaxf(sqrtf(tot), 1e-12f);
    bf16x8 o;
    #pragma unroll
    for (int e = 0; e < 8; ++e) o[e] = (bf16)(f[e] * scale);
    *(bf16x8*)(h + (long)row * D_MODEL + threadIdx.x * 8) = o;
}

__device__ __forceinline__ void conv_body(bf16* __restrict__ xz,
                                          const float* __restrict__ cw,
                                          const float* __restrict__ cb, int idx) {
    const int c8  = idx & 511;
    const int row = idx >> 9;
    const int t   = row & 2047;
    const int c0  = c8 * 8;
    float acc[8];
    float wv[8][4];
    #pragma unroll
    for (int e = 0; e < 8; ++e) {
        float4 f = ((const float4*)cw)[c0 + e];
        wv[e][0] = f.x; wv[e][1] = f.y; wv[e][2] = f.z; wv[e][3] = f.w;
        acc[e] = cb[c0 + e];
    }
    #pragma unroll
    for (int j = 0; j < 4; ++j) {
        if (t + j - 3 >= 0) {
            bf16x8 xv = *(const bf16x8*)(xz + (long)(row + j - 3) * (2*D_INNER) + c0);
            #pragma unroll
            for (int e = 0; e < 8; ++e) acc[e] += (float)xv[e] * wv[e][j];
        }
    }
    bf16* zp = xz + (long)row * (2*D_INNER) + D_INNER + c0;
    bf16x8 zv = *(const bf16x8*)zp;
    bf16x8 yv;
    #pragma unroll
    for (int e = 0; e < 8; ++e) {
        float xc = acc[e];
        float s1 = xc / (1.f + __expf(-xc));
        float z  = (float)zv[e];
        float s2 = z / (1.f + __expf(-z));
        yv[e] = (bf16)(s1 * s2);
    }
    *(bf16x8*)zp = yv;
}

// ---------------- merged elementwise kernels ----------------
__global__ __launch_bounds__(256) void prep_kernel(const float* __restrict__ x,
                                                   bf16* __restrict__ h,
                                                   const float* __restrict__ w,
                                                   bf16* __restrict__ wOut, int n8) {
    if ((int)blockIdx.x < ROWS) rmsnorm_body(x, h, blockIdx.x);
    else f2b_body(w, wOut, (blockIdx.x - ROWS) * 256 + threadIdx.x, n8);
}

__global__ __launch_bounds__(256) void prep2_kernel(const bf16* __restrict__ x2b,
                                                    bf16* __restrict__ h,
                                                    const float* __restrict__ w1,
                                                    bf16* __restrict__ w1o,
                                                    const float* __restrict__ w2,
                                                    bf16* __restrict__ w2o, int n8) {
    if ((int)blockIdx.x < ROWS) rmsnorm_body_b16(x2b, h, blockIdx.x);
    else if ((int)blockIdx.x < 2 * ROWS)
        f2b_body(w1, w1o, (blockIdx.x - ROWS) * 256 + threadIdx.x, n8);
    else
        f2b_body(w2, w2o, (blockIdx.x - 2 * ROWS) * 256 + threadIdx.x, n8);
}

__global__ __launch_bounds__(256) void convf2b_kernel(bf16* __restrict__ xz,
                                                      const float* __restrict__ cw,
                                                      const float* __restrict__ cb,
                                                      const float* __restrict__ w,
                                                      bf16* __restrict__ wOut, int n8) {
    if ((int)blockIdx.x < 16384) conv_body(xz, cw, cb, blockIdx.x * 256 + threadIdx.x);
    else f2b_body(w, wOut, (blockIdx.x - 16384) * 256 + threadIdx.x, n8);
}

// ---------------- bf16 GEMM v12 "2-block": C = A @ B^T (+ epilogue) --------
// 128x128 tile, BK=64, 256 threads = 4 waves (2M x 2N), per-wave 64x64.
// LDS: 2 dbuf x (A 16KB + B 16KB) = 64KB -> TWO blocks per CU (decoupled
// barrier domains; the skewed blocks let ds_read and MFMA pipes overlap --
// the m114 mechanism our single-block 128KB kernel could not exploit).
// Same proven pieces as v11: 128B LDS rows, XOR chunk swizzle with
// inverse-swizzled global source (0 conflicts), counted vmcnt(4)/K-tile
// (retires exactly tile t+1), 2 MFMA phases per K-tile with refills under
// MFMA, T5 setprio, bijective 2D XCD map. All ds_reads drained (lgkm(0))
// before each phase's closing barrier -> no cross-wave read-vs-DMA hazard.
// EPI: 0 = bf16, 1 = relu+bf16, 2 = fp32-res add -> bf16 out,
//      3 = bf16-res add -> fp32 out
template<int EPI>
__global__ __launch_bounds__(256, 2) void gemm_bt(
        const bf16* __restrict__ A, long lda,
        const bf16* __restrict__ B,
        void* __restrict__ C, const void* __restrict__ res,
        int N, int K, int gx) {
    __shared__ __align__(16) char LB[65536];
    const int tid = threadIdx.x;
    const int w   = tid >> 6;
    const int l   = tid & 63;
    const int lr  = l & 15;

    // bijective 2D XCD map: XCDs arranged 4x2, each owns an (gy/4 x gx/2)
    // tile region (gy = nwg/gx; gy%4==0 and gx%2==0 for all our grids)
    const int nwg = gridDim.x;
    const int xcd = blockIdx.x & 7, i = blockIdx.x >> 3;
    const int hw  = gx >> 1;
    const int rh  = (nwg >> 3) / hw;
    const int by  = (xcd >> 1) * rh + i / hw;
    const int bx  = (xcd & 1) * hw + i % hw;
    const long rowBase = (long)by * 128;
    const long colBase = (long)bx * 128;

    // staging: thread covers row w*8 + (l>>3) of each 32-row group,
    // 16B chunk (l&7)^((l>>3)&7) (inverse swizzle on the global source)
    const int srow = w * 8 + (l >> 3);
    const int schk = (l & 7) ^ ((l >> 3) & 7);
    const bf16* aSrc = A + (rowBase + srow) * lda + schk * 8;
    const bf16* bSrc = B + (colBase + srow) * (long)K + schk * 8;
    const long lda32 = 32 * lda;
    const long ldb32 = 32 * (long)K;
    const int  w1024 = w * 1024;

    auto stgA = [&](int DBB, int kt) {   // A tile [128][64] -> 4 loads
        const bf16* s = aSrc + (long)kt * 64;
        gload_lds16(s,            LB + DBB +     0 + w1024);
        gload_lds16(s +   lda32,  LB + DBB +  4096 + w1024);
        gload_lds16(s + 2*lda32,  LB + DBB +  8192 + w1024);
        gload_lds16(s + 3*lda32,  LB + DBB + 12288 + w1024);
    };
    auto stgB = [&](int DBB, int kt) {   // B tile [128][64] -> 4 loads
        const bf16* s = bSrc + (long)kt * 64;
        gload_lds16(s,            LB + DBB + 16384 + w1024);
        gload_lds16(s +   ldb32,  LB + DBB + 20480 + w1024);
        gload_lds16(s + 2*ldb32,  LB + DBB + 24576 + w1024);
        gload_lds16(s + 3*ldb32,  LB + DBB + 28672 + w1024);
    };

    // fragment read offsets (swizzled); frag row & 7 == l & 7
    const int cx0 = (((l >> 4)    ) ^ (l & 7)) << 4;
    const int cx1 = (((l >> 4) + 4) ^ (l & 7)) << 4;
    const int hm = w >> 1;     // wave M half
    const int hn = w & 1;      // wave N half
    int aRow[4], bRow[4];
    #pragma unroll
    for (int m = 0; m < 4; ++m) aRow[m] = (hm * 64 + m * 16 + lr) * 128;
    #pragma unroll
    for (int n = 0; n < 4; ++n) bRow[n] = 16384 + (hn * 64 + n * 16 + lr) * 128;

    const int nt  = K >> 6;
    const int nit = nt >> 1;
    f32x4 acc[4][4] = {};
    bf16x8 AX[4][2], BL[2][2], BH[2][2];

    // prologue: tile0 -> buf0, tile1 -> buf1 (order B,A per tile: FIFO)
    stgB(0, 0);      stgA(0, 0);
    stgB(32768, 1);  stgA(32768, 1);
    asm volatile("s_waitcnt vmcnt(8)" ::: "memory");   // tile 0 landed
    __builtin_amdgcn_s_barrier();
    __builtin_amdgcn_sched_barrier(0);
    #pragma unroll
    for (int m = 0; m < 4; ++m) {
        AX[m][0] = *(const bf16x8*)(LB + aRow[m] + cx0);
        AX[m][1] = *(const bf16x8*)(LB + aRow[m] + cx1);
    }
    #pragma unroll
    for (int n = 0; n < 2; ++n) {
        BL[n][0] = *(const bf16x8*)(LB + bRow[n]     + cx0);
        BL[n][1] = *(const bf16x8*)(LB + bRow[n]     + cx1);
    }
    #pragma unroll
    for (int n = 0; n < 2; ++n) {
        BH[n][0] = *(const bf16x8*)(LB + bRow[n + 2] + cx0);
        BH[n][1] = *(const bf16x8*)(LB + bRow[n + 2] + cx1);
    }
    asm volatile("s_waitcnt lgkmcnt(4)" ::: "memory");  // AX+BL landed
    __builtin_amdgcn_sched_barrier(0);
    __builtin_amdgcn_s_setprio(1);
    #pragma unroll
    for (int m = 0; m < 4; ++m)                          // q1(t0): AX x BL
        #pragma unroll
        for (int n = 0; n < 2; ++n) {
            acc[m][n] = __builtin_amdgcn_mfma_f32_16x16x32_bf16(AX[m][0], BL[n][0], acc[m][n], 0, 0, 0);
            acc[m][n] = __builtin_amdgcn_mfma_f32_16x16x32_bf16(AX[m][1], BL[n][1], acc[m][n], 0, 0, 0);
        }
    __builtin_amdgcn_s_setprio(0);
    asm volatile("s_waitcnt lgkmcnt(0)" ::: "memory");   // BH drained pre-barrier
    __builtin_amdgcn_s_barrier();
    __builtin_amdgcn_sched_barrier(0);

    for (int it = 0; it < nit; ++it) {
        int kA = 2 * it + 2; if (kA >= nt) kA = 0;       // dummy clamp in tail
        int kB = 2 * it + 3; if (kB >= nt) kB = 0;
        #pragma unroll
        for (int db = 0; db < 2; ++db) {
            const int DBB = db * 32768;
            const char* Ln = LB + (DBB ^ 32768);
            const int kst = db ? kB : kA;
            const bool full = (db == 0) || (it < nit - 1);

            // ===== P_A(t): q2 = AX x BH =====
            stgB(DBB, kst);                              // t+2's B into cur
            __builtin_amdgcn_s_setprio(1);
            #pragma unroll
            for (int m = 0; m < 4; ++m)
                #pragma unroll
                for (int n = 0; n < 2; ++n) {
                    acc[m][n + 2] = __builtin_amdgcn_mfma_f32_16x16x32_bf16(AX[m][0], BH[n][0], acc[m][n + 2], 0, 0, 0);
                    acc[m][n + 2] = __builtin_amdgcn_mfma_f32_16x16x32_bf16(AX[m][1], BH[n][1], acc[m][n + 2], 0, 0, 0);
                }
            __builtin_amdgcn_s_setprio(0);
            asm volatile("s_waitcnt vmcnt(4)" ::: "memory");  // t+1 landed (FIFO)
            __builtin_amdgcn_s_barrier();
            __builtin_amdgcn_sched_barrier(0);

            // ===== P_B(t): read t+1, q1(t+1) = AX x BL =====
            if (full) {
                #pragma unroll
                for (int m = 0; m < 4; ++m) {             // AX <- A(t+1)
                    AX[m][0] = *(const bf16x8*)(Ln + aRow[m] + cx0);
                    AX[m][1] = *(const bf16x8*)(Ln + aRow[m] + cx1);
                }
                #pragma unroll
                for (int n = 0; n < 2; ++n) {             // BL <- B0(t+1)
                    BL[n][0] = *(const bf16x8*)(Ln + bRow[n]     + cx0);
                    BL[n][1] = *(const bf16x8*)(Ln + bRow[n]     + cx1);
                }
            }
            stgA(DBB, kst);                              // t+2's A into cur
            if (full) {
                #pragma unroll
                for (int n = 0; n < 2; ++n) {             // BH <- B1(t+1), last
                    BH[n][0] = *(const bf16x8*)(Ln + bRow[n + 2] + cx0);
                    BH[n][1] = *(const bf16x8*)(Ln + bRow[n + 2] + cx1);
                }
                asm volatile("s_waitcnt lgkmcnt(4)" ::: "memory");  // AX+BL done
                __builtin_amdgcn_sched_barrier(0);
                __builtin_amdgcn_s_setprio(1);
                #pragma unroll
                for (int m = 0; m < 4; ++m)
                    #pragma unroll
                    for (int n = 0; n < 2; ++n) {
                        acc[m][n] = __builtin_amdgcn_mfma_f32_16x16x32_bf16(AX[m][0], BL[n][0], acc[m][n], 0, 0, 0);
                        acc[m][n] = __builtin_amdgcn_mfma_f32_16x16x32_bf16(AX[m][1], BL[n][1], acc[m][n], 0, 0, 0);
                    }
                __builtin_amdgcn_s_setprio(0);
                asm volatile("s_waitcnt lgkmcnt(0)" ::: "memory");  // BH drained
            }
            __builtin_amdgcn_s_barrier();
            __builtin_amdgcn_sched_barrier(0);
        }
    }

    // drain dummy prefetch DMAs; then LDS is safe to reuse
    asm volatile("s_waitcnt vmcnt(0)" ::: "memory");
    __builtin_amdgcn_s_barrier();

    // epilogue: per-wave private 16KB LDS region, chunk-XOR swizzle
    const int lg = l >> 4;
    const long wrow = rowBase + hm * 64;
    const long wcol = colBase + hn * 64;
    char* ep = LB + w * 16384;

    if (EPI == 3) {
        // bf16 res add -> fp32 out: [64][64] f32 = 16KB
        const bf16* rb = (const bf16*)res;
        #pragma unroll
        for (int m = 0; m < 4; ++m) {
            #pragma unroll
            for (int n = 0; n < 4; ++n) {
                f32x4 v = acc[m][n];
                #pragma unroll
                for (int r = 0; r < 4; ++r) {
                    int rowr = m * 16 + lg * 4 + r;
                    int chnk = (n * 4 + (lr >> 2)) ^ (rowr & 7);
                    *(float*)(ep + rowr * 256 + chnk * 16 + (lr & 3) * 4) = v[r];
                }
            }
        }
        asm volatile("s_waitcnt lgkmcnt(0)" ::: "memory");
        #pragma unroll
        for (int i = 0; i < 16; ++i) {
            int rr = i * 4 + (l >> 4);
            float4 lv = *(float4*)(ep + rr * 256 + (((l & 15) ^ (rr & 7)) * 16));
            long off = (wrow + rr) * N + wcol + (l & 15) * 4;
            bf16x4 rv = *(const bf16x4*)(rb + off);
            lv.x += (float)rv[0]; lv.y += (float)rv[1];
            lv.z += (float)rv[2]; lv.w += (float)rv[3];
            *(float4*)((float*)C + off) = lv;
        }
    } else {
        // bf16 out (EPI 0/1/2): [64][64] bf16 = 8KB
        const float* rf = (const float*)res;
        #pragma unroll
        for (int m = 0; m < 4; ++m) {
            #pragma unroll
            for (int n = 0; n < 4; ++n) {
                f32x4 v = acc[m][n];
                #pragma unroll
                for (int r = 0; r < 4; ++r) {
                    int rowr = m * 16 + lg * 4 + r;
                    int chnk = (n * 2 + (lr >> 3)) ^ (rowr & 7);
                    float val = v[r];
                    if (EPI == 1) val = fmaxf(val, 0.f);
                    if (EPI == 2) val += rf[(wrow + rowr) * N + wcol + n * 16 + lr];
                    *(bf16*)(ep + rowr * 128 + chnk * 16 + (lr & 7) * 2) = (bf16)val;
                }
            }
        }
        asm volatile("s_waitcnt lgkmcnt(0)" ::: "memory");
        #pragma unroll
        for (int i = 0; i < 8; ++i) {
            int rr = i * 8 + (l >> 3);
            uint4 lv = *(uint4*)(ep + rr * 128 + (((l & 7) ^ (rr & 7)) * 16));
            *(uint4*)((bf16*)C + (wrow + rr) * N + wcol + (l & 7) * 8) = lv;
        }
    }
}

extern "C" void kernel_launch(void* const* d_in, const int* in_sizes, int n_in,
                              void* d_out, int out_size, void* d_ws, size_t ws_size,
                              hipStream_t stream) {
    const float* x      = (const float*)d_in[0];
    const float* W_in   = (const float*)d_in[1];
    const float* cw     = (const float*)d_in[2];
    const float* cb     = (const float*)d_in[3];
    const float* W_out  = (const float*)d_in[4];
    const float* W_mlp1 = (const float*)d_in[5];
    const float* W_mlp2 = (const float*)d_in[6];
    float* out = (float*)d_out;

    char* ws  = (char*)d_ws;
    bf16* wW  = (bf16*)(ws);                    // 33.55 MB
    bf16* h   = (bf16*)(ws + 33554432);         // 33.55 MB
    bf16* xz  = (bf16*)(ws + 67108864);         // 134.2 MB (xz / m1)
    bf16* x2b = (bf16*)(ws + 201326592);        // 33.55 MB (bf16 residual)
    bf16* wW2 = (bf16*)(ws + 234881024);        // 33.55 MB (W_mlp2 bf16)
    bf16* y   = xz + D_INNER;                   // z-half in place, lda = 8192
    bf16* m1  = xz;

    dim3 blk(256);

    // mamba branch
    prep_kernel<<<dim3(ROWS + 8192), blk, 0, stream>>>(x, h, W_in, wW, 16777216/8);
    gemm_bt<0><<<dim3(4096), blk, 0, stream>>>(h, D_MODEL, wW, xz, nullptr, 2*D_INNER, D_MODEL, 64);
    convf2b_kernel<<<dim3(16384 + 4096), blk, 0, stream>>>(xz, cw, cb, W_out, wW, 8388608/8);
    gemm_bt<2><<<dim3(1024), blk, 0, stream>>>(y, 2*D_INNER, wW, x2b, x, D_MODEL, D_INNER, 16);

    // mlp branch
    prep2_kernel<<<dim3(3 * ROWS), blk, 0, stream>>>(x2b, h, W_mlp1, wW, W_mlp2, wW2, 16777216/8);
    gemm_bt<1><<<dim3(4096), blk, 0, stream>>>(h, D_MODEL, wW, m1, nullptr, 4*D_MODEL, D_MODEL, 64);
    gemm_bt<3><<<dim3(1024), blk, 0, stream>>>(m1, 4*D_MODEL, wW2, out, x2b, D_MODEL, 4*D_MODEL, 16);
}

// Round 15
// 936.309 us; speedup vs baseline: 1.3607x; 1.3607x over previous
//
#include <hip/hip_runtime.h>
#include <hip/hip_bf16.h>

typedef __bf16 bf16;
typedef __bf16 bf16x8 __attribute__((ext_vector_type(8)));
typedef __bf16 bf16x4 __attribute__((ext_vector_type(4)));
typedef float f32x4 __attribute__((ext_vector_type(4)));

#define D_MODEL 2048
#define D_INNER 4096
#define ROWS    8192   // B*T

__device__ __forceinline__ void gload_lds16(const void* g, void* l) {
    __builtin_amdgcn_global_load_lds(
        (const __attribute__((address_space(1))) void*)g,
        (__attribute__((address_space(3))) void*)l, 16, 0, 0);
}

// ---------------- device bodies ----------------
__device__ __forceinline__ void f2b_body(const float* __restrict__ in,
                                         bf16* __restrict__ out, int i, int n8) {
    if (i >= n8) return;
    long base = (long)i * 8;
    float4 a = *(const float4*)(in + base);
    float4 b = *(const float4*)(in + base + 4);
    bf16x8 o;
    o[0] = (bf16)a.x; o[1] = (bf16)a.y; o[2] = (bf16)a.z; o[3] = (bf16)a.w;
    o[4] = (bf16)b.x; o[5] = (bf16)b.y; o[6] = (bf16)b.z; o[7] = (bf16)b.w;
    *(bf16x8*)(out + base) = o;
}

__device__ __forceinline__ void rmsnorm_body(const float* __restrict__ x,
                                             bf16* __restrict__ h, int row) {
    const float* xr = x + (long)row * D_MODEL;
    float4 v0 = ((const float4*)xr)[threadIdx.x * 2];
    float4 v1 = ((const float4*)xr)[threadIdx.x * 2 + 1];
    float ss = v0.x*v0.x + v0.y*v0.y + v0.z*v0.z + v0.w*v0.w
             + v1.x*v1.x + v1.y*v1.y + v1.z*v1.z + v1.w*v1.w;
    #pragma unroll
    for (int o = 32; o; o >>= 1) ss += __shfl_xor(ss, o, 64);
    __shared__ float red[4];
    if ((threadIdx.x & 63) == 0) red[threadIdx.x >> 6] = ss;
    __syncthreads();
    float tot = red[0] + red[1] + red[2] + red[3];
    float scale = 45.254834f / fmaxf(sqrtf(tot), 1e-12f);
    bf16x8 o;
    o[0] = (bf16)(v0.x*scale); o[1] = (bf16)(v0.y*scale);
    o[2] = (bf16)(v0.z*scale); o[3] = (bf16)(v0.w*scale);
    o[4] = (bf16)(v1.x*scale); o[5] = (bf16)(v1.y*scale);
    o[6] = (bf16)(v1.z*scale); o[7] = (bf16)(v1.w*scale);
    *(bf16x8*)(h + (long)row * D_MODEL + threadIdx.x * 8) = o;
}

__device__ __forceinline__ void rmsnorm_body_b16(const bf16* __restrict__ x,
                                                 bf16* __restrict__ h, int row) {
    const bf16* xr = x + (long)row * D_MODEL;
    bf16x8 v = *(const bf16x8*)(xr + threadIdx.x * 8);
    float f[8];
    float ss = 0.f;
    #pragma unroll
    for (int e = 0; e < 8; ++e) { f[e] = (float)v[e]; ss += f[e] * f[e]; }
    #pragma unroll
    for (int o = 32; o; o >>= 1) ss += __shfl_xor(ss, o, 64);
    __shared__ float red[4];
    if ((threadIdx.x & 63) == 0) red[threadIdx.x >> 6] = ss;
    __syncthreads();
    float tot = red[0] + red[1] + red[2] + red[3];
    float scale = 45.254834f / fmaxf(sqrtf(tot), 1e-12f);
    bf16x8 o;
    #pragma unroll
    for (int e = 0; e < 8; ++e) o[e] = (bf16)(f[e] * scale);
    *(bf16x8*)(h + (long)row * D_MODEL + threadIdx.x * 8) = o;
}

__device__ __forceinline__ void conv_body(bf16* __restrict__ xz,
                                          const float* __restrict__ cw,
                                          const float* __restrict__ cb, int idx) {
    const int c8  = idx & 511;
    const int row = idx >> 9;
    const int t   = row & 2047;
    const int c0  = c8 * 8;
    float acc[8];
    float wv[8][4];
    #pragma unroll
    for (int e = 0; e < 8; ++e) {
        float4 f = ((const float4*)cw)[c0 + e];
        wv[e][0] = f.x; wv[e][1] = f.y; wv[e][2] = f.z; wv[e][3] = f.w;
        acc[e] = cb[c0 + e];
    }
    #pragma unroll
    for (int j = 0; j < 4; ++j) {
        if (t + j - 3 >= 0) {
            bf16x8 xv = *(const bf16x8*)(xz + (long)(row + j - 3) * (2*D_INNER) + c0);
            #pragma unroll
            for (int e = 0; e < 8; ++e) acc[e] += (float)xv[e] * wv[e][j];
        }
    }
    bf16* zp = xz + (long)row * (2*D_INNER) + D_INNER + c0;
    bf16x8 zv = *(const bf16x8*)zp;
    bf16x8 yv;
    #pragma unroll
    for (int e = 0; e < 8; ++e) {
        float xc = acc[e];
        float s1 = xc / (1.f + __expf(-xc));
        float z  = (float)zv[e];
        float s2 = z / (1.f + __expf(-z));
        yv[e] = (bf16)(s1 * s2);
    }
    *(bf16x8*)zp = yv;
}

// ---------------- merged elementwise kernels ----------------
__global__ __launch_bounds__(256) void prep_kernel(const float* __restrict__ x,
                                                   bf16* __restrict__ h,
                                                   const float* __restrict__ w,
                                                   bf16* __restrict__ wOut, int n8) {
    if ((int)blockIdx.x < ROWS) rmsnorm_body(x, h, blockIdx.x);
    else f2b_body(w, wOut, (blockIdx.x - ROWS) * 256 + threadIdx.x, n8);
}

__global__ __launch_bounds__(256) void prep2_kernel(const bf16* __restrict__ x2b,
                                                    bf16* __restrict__ h,
                                                    const float* __restrict__ w1,
                                                    bf16* __restrict__ w1o,
                                                    const float* __restrict__ w2,
                                                    bf16* __restrict__ w2o, int n8) {
    if ((int)blockIdx.x < ROWS) rmsnorm_body_b16(x2b, h, blockIdx.x);
    else if ((int)blockIdx.x < 2 * ROWS)
        f2b_body(w1, w1o, (blockIdx.x - ROWS) * 256 + threadIdx.x, n8);
    else
        f2b_body(w2, w2o, (blockIdx.x - 2 * ROWS) * 256 + threadIdx.x, n8);
}

__global__ __launch_bounds__(256) void convf2b_kernel(bf16* __restrict__ xz,
                                                      const float* __restrict__ cw,
                                                      const float* __restrict__ cb,
                                                      const float* __restrict__ w,
                                                      bf16* __restrict__ wOut, int n8) {
    if ((int)blockIdx.x < 16384) conv_body(xz, cw, cb, blockIdx.x * 256 + threadIdx.x);
    else f2b_body(w, wOut, (blockIdx.x - 16384) * 256 + threadIdx.x, n8);
}

// ---------------- bf16 GEMM v11 (proven best): C = A @ B^T ------------------
// 256x256 tile, BK=64, 512 threads = 8 waves (2M x 4N), per-wave 128x64.
// 2 dbuf x 64KB, XOR chunk swizzle (inverse-swizzled global source, 0
// conflicts), 2 super-phases/K-tile with refills under MFMA, counted
// vmcnt(4)/K-tile (FIFO B0,B1,A0,A1 -> retires exactly tile t+1), T5
// setprio, bijective 2D XCD map (gx==32: 4x2 XCD regions).
// EPI: 0 = bf16, 1 = relu+bf16, 2 = fp32-res add -> bf16 out,
//      3 = bf16-res add -> fp32 out
template<int EPI>
__global__ __launch_bounds__(512, 2) void gemm_bt(
        const bf16* __restrict__ A, long lda,
        const bf16* __restrict__ B,
        void* __restrict__ C, const void* __restrict__ res,
        int N, int K, int gx) {
    __shared__ __align__(16) char LB[131072];
    const int tid = threadIdx.x;
    const int w   = tid >> 6;
    const int l   = tid & 63;
    const int lr  = l & 15;

    int bx, by;
    if (gx == 32) {
        const int xcd = blockIdx.x & 7, i = blockIdx.x >> 3;
        by = (xcd >> 1) * 8 + (i >> 4);
        bx = (xcd & 1) * 16 + (i & 15);
    } else {
        const int qq = gridDim.x >> 3;
        const int sw = (blockIdx.x & 7) * qq + (blockIdx.x >> 3);
        bx = sw % gx; by = sw / gx;
    }
    const long rowBase = (long)by * 256;
    const long colBase = (long)bx * 256;

    const int srow = w * 8 + (l >> 3);
    const int schk = (l & 7) ^ ((l >> 3) & 7);
    const bf16* aSrc = A + (rowBase + srow) * lda + schk * 8;
    const bf16* bSrc = B + (colBase + srow) * (long)K + schk * 8;
    const long lda64 = 64 * lda;
    const long ldb64 = 64 * (long)K;
    const int  w1024 = w * 1024;

    auto stgA0 = [&](int DBB, int kt) {
        const bf16* s = aSrc + (long)kt * 64;
        gload_lds16(s,            LB + DBB +     0 + w1024);
        gload_lds16(s +   lda64,  LB + DBB +  8192 + w1024);
    };
    auto stgA1 = [&](int DBB, int kt) {
        const bf16* s = aSrc + (long)kt * 64;
        gload_lds16(s + 2*lda64,  LB + DBB + 16384 + w1024);
        gload_lds16(s + 3*lda64,  LB + DBB + 24576 + w1024);
    };
    auto stgB0 = [&](int DBB, int kt) {
        const bf16* s = bSrc + (long)kt * 64;
        gload_lds16(s,            LB + DBB + 32768 + w1024);
        gload_lds16(s +   ldb64,  LB + DBB + 40960 + w1024);
    };
    auto stgB1 = [&](int DBB, int kt) {
        const bf16* s = bSrc + (long)kt * 64;
        gload_lds16(s + 2*ldb64,  LB + DBB + 49152 + w1024);
        gload_lds16(s + 3*ldb64,  LB + DBB + 57344 + w1024);
    };

    const int cx0 = (((l >> 4)    ) ^ (l & 7)) << 4;
    const int cx1 = (((l >> 4) + 4) ^ (l & 7)) << 4;
    const int hm = w >> 2;
    const int q  = w & 3;
    int aRow[8], bRow[4];
    #pragma unroll
    for (int m = 0; m < 8; ++m) aRow[m] = hm * 16384 + (m * 16 + lr) * 128;
    #pragma unroll
    for (int n = 0; n < 4; ++n)
        bRow[n] = 32768 + (q >> 1) * 16384 + ((q & 1) * 64 + n * 16 + lr) * 128;

    const int nt  = K >> 6;
    const int nit = nt >> 1;
    f32x4 acc[8][4] = {};
    bf16x8 AX[4][2], BL[2][2], BH[2][2];

    stgB0(0, 0); stgB1(0, 0); stgA0(0, 0); stgA1(0, 0);
    stgB0(65536, 1); stgB1(65536, 1); stgA0(65536, 1); stgA1(65536, 1);
    asm volatile("s_waitcnt vmcnt(8)" ::: "memory");
    __builtin_amdgcn_s_barrier();
    __builtin_amdgcn_sched_barrier(0);
    #pragma unroll
    for (int m = 0; m < 4; ++m) {
        AX[m][0] = *(const bf16x8*)(LB + aRow[m] + cx0);
        AX[m][1] = *(const bf16x8*)(LB + aRow[m] + cx1);
    }
    #pragma unroll
    for (int n = 0; n < 2; ++n) {
        BL[n][0] = *(const bf16x8*)(LB + bRow[n]     + cx0);
        BL[n][1] = *(const bf16x8*)(LB + bRow[n]     + cx1);
    }
    #pragma unroll
    for (int n = 0; n < 2; ++n) {
        BH[n][0] = *(const bf16x8*)(LB + bRow[n + 2] + cx0);
        BH[n][1] = *(const bf16x8*)(LB + bRow[n + 2] + cx1);
    }
    asm volatile("s_waitcnt lgkmcnt(4)" ::: "memory");
    __builtin_amdgcn_sched_barrier(0);
    __builtin_amdgcn_s_setprio(1);
    #pragma unroll
    for (int m = 0; m < 4; ++m)
        #pragma unroll
        for (int n = 0; n < 2; ++n) {
            acc[m][n] = __builtin_amdgcn_mfma_f32_16x16x32_bf16(AX[m][0], BL[n][0], acc[m][n], 0, 0, 0);
            acc[m][n] = __builtin_amdgcn_mfma_f32_16x16x32_bf16(AX[m][1], BL[n][1], acc[m][n], 0, 0, 0);
        }
    __builtin_amdgcn_s_setprio(0);
    __builtin_amdgcn_s_barrier();

    for (int it = 0; it < nit; ++it) {
        int kA = 2 * it + 2; if (kA >= nt) kA = 0;
        int kB = 2 * it + 3; if (kB >= nt) kB = 0;
        #pragma unroll
        for (int db = 0; db < 2; ++db) {
            const int DBB = db * 65536;
            const char* Lb = LB + DBB;
            const char* Ln = LB + (DBB ^ 65536);
            const int kst = db ? kB : kA;
            const bool full = (db == 0) || (it < nit - 1);

            // ================= P_A =================
            stgB0(DBB, kst);
            __builtin_amdgcn_s_setprio(1);
            #pragma unroll
            for (int m = 0; m < 4; ++m) {                     // q2: A0 x BH
                #pragma unroll
                for (int n = 0; n < 2; ++n) {
                    acc[m][n + 2] = __builtin_amdgcn_mfma_f32_16x16x32_bf16(AX[m][0], BH[n][0], acc[m][n + 2], 0, 0, 0);
                    acc[m][n + 2] = __builtin_amdgcn_mfma_f32_16x16x32_bf16(AX[m][1], BH[n][1], acc[m][n + 2], 0, 0, 0);
                }
                AX[m][0] = *(const bf16x8*)(Lb + aRow[m + 4] + cx0);
                AX[m][1] = *(const bf16x8*)(Lb + aRow[m + 4] + cx1);
            }
            __builtin_amdgcn_s_setprio(0);
            stgB1(DBB, kst);
            asm volatile("s_waitcnt lgkmcnt(0)" ::: "memory");
            __builtin_amdgcn_sched_barrier(0);
            __builtin_amdgcn_s_setprio(1);
            #pragma unroll
            for (int m = 0; m < 4; ++m)                       // q3: A1 x BH
                #pragma unroll
                for (int n = 0; n < 2; ++n) {
                    acc[m + 4][n + 2] = __builtin_amdgcn_mfma_f32_16x16x32_bf16(AX[m][0], BH[n][0], acc[m + 4][n + 2], 0, 0, 0);
                    acc[m + 4][n + 2] = __builtin_amdgcn_mfma_f32_16x16x32_bf16(AX[m][1], BH[n][1], acc[m + 4][n + 2], 0, 0, 0);
                }
            __builtin_amdgcn_s_setprio(0);
            asm volatile("s_waitcnt vmcnt(4)" ::: "memory");  // t+1 landed (FIFO)
            __builtin_amdgcn_s_barrier();
            __builtin_amdgcn_sched_barrier(0);

            // ================= P_B =================
            __builtin_amdgcn_s_setprio(1);
            #pragma unroll
            for (int m = 0; m < 4; ++m) {                     // q4: A1 x BL
                #pragma unroll
                for (int n = 0; n < 2; ++n) {
                    acc[m + 4][n] = __builtin_amdgcn_mfma_f32_16x16x32_bf16(AX[m][0], BL[n][0], acc[m + 4][n], 0, 0, 0);
                    acc[m + 4][n] = __builtin_amdgcn_mfma_f32_16x16x32_bf16(AX[m][1], BL[n][1], acc[m + 4][n], 0, 0, 0);
                }
                if (full) {
                    AX[m][0] = *(const bf16x8*)(Ln + aRow[m] + cx0);
                    AX[m][1] = *(const bf16x8*)(Ln + aRow[m] + cx1);
                    if (m < 2) {                               // BH refill under q4
                        BH[m][0] = *(const bf16x8*)(Ln + bRow[m + 2] + cx0);
                        BH[m][1] = *(const bf16x8*)(Ln + bRow[m + 2] + cx1);
                    }
                }
            }
            __builtin_amdgcn_s_setprio(0);
            __builtin_amdgcn_sched_barrier(0);
            stgA0(DBB, kst);
            if (full) {
                #pragma unroll
                for (int n = 0; n < 2; ++n) {                  // BL <- B0(t+1)
                    BL[n][0] = *(const bf16x8*)(Ln + bRow[n]     + cx0);
                    BL[n][1] = *(const bf16x8*)(Ln + bRow[n]     + cx1);
                }
            }
            stgA1(DBB, kst);
            if (full) {
                asm volatile("s_waitcnt lgkmcnt(0)" ::: "memory");
                __builtin_amdgcn_sched_barrier(0);
                __builtin_amdgcn_s_setprio(1);
                #pragma unroll
                for (int m = 0; m < 4; ++m)                   // q1(t+1): A0 x B0
                    #pragma unroll
                    for (int n = 0; n < 2; ++n) {
                        acc[m][n] = __builtin_amdgcn_mfma_f32_16x16x32_bf16(AX[m][0], BL[n][0], acc[m][n], 0, 0, 0);
                        acc[m][n] = __builtin_amdgcn_mfma_f32_16x16x32_bf16(AX[m][1], BL[n][1], acc[m][n], 0, 0, 0);
                    }
                __builtin_amdgcn_s_setprio(0);
            }
            __builtin_amdgcn_s_barrier();
        }
    }

    asm volatile("s_waitcnt vmcnt(0)" ::: "memory");
    __builtin_amdgcn_s_barrier();

    // epilogue
    const int lg = l >> 4;
    const long wrow = rowBase + hm * 128;
    const long wcol = colBase + q * 64;
    char* ep = LB + w * 16384;

    if (EPI == 3) {
        // bf16 res add -> fp32 out, two 64-row passes via fp32 LDS
        const bf16* rb = (const bf16*)res;
        #pragma unroll
        for (int mh = 0; mh < 2; ++mh) {
            #pragma unroll
            for (int m = 0; m < 4; ++m) {
                #pragma unroll
                for (int n = 0; n < 4; ++n) {
                    f32x4 v = acc[mh * 4 + m][n];
                    #pragma unroll
                    for (int r = 0; r < 4; ++r) {
                        int rowr = m * 16 + lg * 4 + r;
                        int chnk = (n * 4 + (lr >> 2)) ^ (rowr & 7);
                        *(float*)(ep + rowr * 256 + chnk * 16 + (lr & 3) * 4) = v[r];
                    }
                }
            }
            asm volatile("s_waitcnt lgkmcnt(0)" ::: "memory");
            #pragma unroll
            for (int i = 0; i < 16; ++i) {
                int rr = i * 4 + (l >> 4);
                float4 lv = *(float4*)(ep + rr * 256 + (((l & 15) ^ (rr & 7)) * 16));
                long off = (wrow + mh * 64 + rr) * N + wcol + (l & 15) * 4;
                bf16x4 rv = *(const bf16x4*)(rb + off);
                lv.x += (float)rv[0]; lv.y += (float)rv[1];
                lv.z += (float)rv[2]; lv.w += (float)rv[3];
                *(float4*)((float*)C + off) = lv;
            }
            if (mh == 0) { asm volatile("s_waitcnt lgkmcnt(0) vmcnt(0)" ::: "memory"); }
        }
    } else {
        // bf16 out (EPI 0/1/2), single pass [128][64] bf16 LDS
        const float* rf = (const float*)res;
        #pragma unroll
        for (int m = 0; m < 8; ++m) {
            #pragma unroll
            for (int n = 0; n < 4; ++n) {
                f32x4 v = acc[m][n];
                #pragma unroll
                for (int r = 0; r < 4; ++r) {
                    int rowr = m * 16 + lg * 4 + r;
                    int chnk = (n * 2 + (lr >> 3)) ^ (rowr & 7);
                    float val = v[r];
                    if (EPI == 1) val = fmaxf(val, 0.f);
                    if (EPI == 2) val += rf[(wrow + rowr) * N + wcol + n * 16 + lr];
                    *(bf16*)(ep + rowr * 128 + chnk * 16 + (lr & 7) * 2) = (bf16)val;
                }
            }
        }
        asm volatile("s_waitcnt lgkmcnt(0)" ::: "memory");
        #pragma unroll
        for (int i = 0; i < 16; ++i) {
            int rr = i * 8 + (l >> 3);
            uint4 lv = *(uint4*)(ep + rr * 128 + (((l & 7) ^ (rr & 7)) * 16));
            *(uint4*)((bf16*)C + (wrow + rr) * N + wcol + (l & 7) * 8) = lv;
        }
    }
}

extern "C" void kernel_launch(void* const* d_in, const int* in_sizes, int n_in,
                              void* d_out, int out_size, void* d_ws, size_t ws_size,
                              hipStream_t stream) {
    const float* x      = (const float*)d_in[0];
    const float* W_in   = (const float*)d_in[1];
    const float* cw     = (const float*)d_in[2];
    const float* cb     = (const float*)d_in[3];
    const float* W_out  = (const float*)d_in[4];
    const float* W_mlp1 = (const float*)d_in[5];
    const float* W_mlp2 = (const float*)d_in[6];
    float* out = (float*)d_out;

    char* ws  = (char*)d_ws;
    bf16* wW  = (bf16*)(ws);                    // 33.55 MB
    bf16* h   = (bf16*)(ws + 33554432);         // 33.55 MB
    bf16* xz  = (bf16*)(ws + 67108864);         // 134.2 MB (xz / m1)
    bf16* x2b = (bf16*)(ws + 201326592);        // 33.55 MB (bf16 residual)
    bf16* wW2 = (bf16*)(ws + 234881024);        // 33.55 MB (W_mlp2 bf16)
    bf16* y   = xz + D_INNER;                   // z-half in place, lda = 8192
    bf16* m1  = xz;

    dim3 blk(256);
    dim3 gblk(512);

    // mamba branch
    prep_kernel<<<dim3(ROWS + 8192), blk, 0, stream>>>(x, h, W_in, wW, 16777216/8);
    gemm_bt<0><<<dim3(1024), gblk, 0, stream>>>(h, D_MODEL, wW, xz, nullptr, 2*D_INNER, D_MODEL, 32);
    convf2b_kernel<<<dim3(16384 + 4096), blk, 0, stream>>>(xz, cw, cb, W_out, wW, 8388608/8);
    gemm_bt<2><<<dim3(256), gblk, 0, stream>>>(y, 2*D_INNER, wW, x2b, x, D_MODEL, D_INNER, 8);

    // mlp branch
    prep2_kernel<<<dim3(3 * ROWS), blk, 0, stream>>>(x2b, h, W_mlp1, wW, W_mlp2, wW2, 16777216/8);
    gemm_bt<1><<<dim3(1024), gblk, 0, stream>>>(h, D_MODEL, wW, m1, nullptr, 4*D_MODEL, D_MODEL, 32);
    gemm_bt<3><<<dim3(256), gblk, 0, stream>>>(m1, 4*D_MODEL, wW2, out, x2b, D_MODEL, 4*D_MODEL, 8);
}

// Round 16
// 863.939 us; speedup vs baseline: 1.4747x; 1.0838x over previous
//
#include <hip/hip_runtime.h>
#include <hip/hip_bf16.h>

typedef __bf16 bf16;
typedef __bf16 bf16x8 __attribute__((ext_vector_type(8)));
typedef __bf16 bf16x4 __attribute__((ext_vector_type(4)));
typedef float f32x4 __attribute__((ext_vector_type(4)));

#define D_MODEL 2048
#define D_INNER 4096
#define ROWS    8192   // B*T

__device__ __forceinline__ void gload_lds16(const void* g, void* l) {
    __builtin_amdgcn_global_load_lds(
        (const __attribute__((address_space(1))) void*)g,
        (__attribute__((address_space(3))) void*)l, 16, 0, 0);
}

// ---------------- device bodies ----------------
__device__ __forceinline__ void f2b_body(const float* __restrict__ in,
                                         bf16* __restrict__ out, int i, int n8) {
    if (i >= n8) return;
    long base = (long)i * 8;
    float4 a = *(const float4*)(in + base);
    float4 b = *(const float4*)(in + base + 4);
    bf16x8 o;
    o[0] = (bf16)a.x; o[1] = (bf16)a.y; o[2] = (bf16)a.z; o[3] = (bf16)a.w;
    o[4] = (bf16)b.x; o[5] = (bf16)b.y; o[6] = (bf16)b.z; o[7] = (bf16)b.w;
    *(bf16x8*)(out + base) = o;
}

__device__ __forceinline__ void rmsnorm_body(const float* __restrict__ x,
                                             bf16* __restrict__ h, int row) {
    const float* xr = x + (long)row * D_MODEL;
    float4 v0 = ((const float4*)xr)[threadIdx.x * 2];
    float4 v1 = ((const float4*)xr)[threadIdx.x * 2 + 1];
    float ss = v0.x*v0.x + v0.y*v0.y + v0.z*v0.z + v0.w*v0.w
             + v1.x*v1.x + v1.y*v1.y + v1.z*v1.z + v1.w*v1.w;
    #pragma unroll
    for (int o = 32; o; o >>= 1) ss += __shfl_xor(ss, o, 64);
    __shared__ float red[4];
    if ((threadIdx.x & 63) == 0) red[threadIdx.x >> 6] = ss;
    __syncthreads();
    float tot = red[0] + red[1] + red[2] + red[3];
    float scale = 45.254834f / fmaxf(sqrtf(tot), 1e-12f);
    bf16x8 o;
    o[0] = (bf16)(v0.x*scale); o[1] = (bf16)(v0.y*scale);
    o[2] = (bf16)(v0.z*scale); o[3] = (bf16)(v0.w*scale);
    o[4] = (bf16)(v1.x*scale); o[5] = (bf16)(v1.y*scale);
    o[6] = (bf16)(v1.z*scale); o[7] = (bf16)(v1.w*scale);
    *(bf16x8*)(h + (long)row * D_MODEL + threadIdx.x * 8) = o;
}

__device__ __forceinline__ void rmsnorm_body_b16(const bf16* __restrict__ x,
                                                 bf16* __restrict__ h, int row) {
    const bf16* xr = x + (long)row * D_MODEL;
    bf16x8 v = *(const bf16x8*)(xr + threadIdx.x * 8);
    float f[8];
    float ss = 0.f;
    #pragma unroll
    for (int e = 0; e < 8; ++e) { f[e] = (float)v[e]; ss += f[e] * f[e]; }
    #pragma unroll
    for (int o = 32; o; o >>= 1) ss += __shfl_xor(ss, o, 64);
    __shared__ float red[4];
    if ((threadIdx.x & 63) == 0) red[threadIdx.x >> 6] = ss;
    __syncthreads();
    float tot = red[0] + red[1] + red[2] + red[3];
    float scale = 45.254834f / fmaxf(sqrtf(tot), 1e-12f);
    bf16x8 o;
    #pragma unroll
    for (int e = 0; e < 8; ++e) o[e] = (bf16)(f[e] * scale);
    *(bf16x8*)(h + (long)row * D_MODEL + threadIdx.x * 8) = o;
}

// 4-row depthwise causal conv + SiLU gate: each thread computes rows
// r0..r0+3 (same batch; T=2048 divisible by 4) for 8 channels, loading
// 7 input rows once (vs 16 loads in the 1-row version).
__device__ __forceinline__ void conv4_body(bf16* __restrict__ xz,
                                           const float* __restrict__ cw,
                                           const float* __restrict__ cb, int idx) {
    const int c8  = idx & 511;
    const int grp = idx >> 9;          // 0..2047
    const int r0  = grp * 4;
    const int t0  = r0 & 2047;         // time position within batch
    const int c0  = c8 * 8;
    float wv[8][4];
    float bias[8];
    #pragma unroll
    for (int e = 0; e < 8; ++e) {
        float4 f = ((const float4*)cw)[c0 + e];
        wv[e][0] = f.x; wv[e][1] = f.y; wv[e][2] = f.z; wv[e][3] = f.w;
        bias[e] = cb[c0 + e];
    }
    bf16x8 xv[7];
    #pragma unroll
    for (int d = 0; d < 7; ++d) {
        bf16x8 z8 = {};
        xv[d] = z8;
        if (t0 + d - 3 >= 0)
            xv[d] = *(const bf16x8*)(xz + (long)(r0 + d - 3) * (2*D_INNER) + c0);
    }
    #pragma unroll
    for (int i = 0; i < 4; ++i) {
        bf16* zp = xz + (long)(r0 + i) * (2*D_INNER) + D_INNER + c0;
        bf16x8 zv = *(const bf16x8*)zp;
        bf16x8 yv;
        #pragma unroll
        for (int e = 0; e < 8; ++e) {
            float acc = bias[e];
            #pragma unroll
            for (int j = 0; j < 4; ++j)
                acc += (float)xv[i + j][e] * wv[e][j];
            float s1 = acc / (1.f + __expf(-acc));
            float z  = (float)zv[e];
            float s2 = z / (1.f + __expf(-z));
            yv[e] = (bf16)(s1 * s2);
        }
        *(bf16x8*)zp = yv;
    }
}

// ---------------- merged elementwise kernels ----------------
__global__ __launch_bounds__(256) void prep_kernel(const float* __restrict__ x,
                                                   bf16* __restrict__ h,
                                                   const float* __restrict__ w,
                                                   bf16* __restrict__ wOut, int n8) {
    if ((int)blockIdx.x < ROWS) rmsnorm_body(x, h, blockIdx.x);
    else f2b_body(w, wOut, (blockIdx.x - ROWS) * 256 + threadIdx.x, n8);
}

// rmsnorm_b16 (8192) + f2b W_mlp1 (8192)
__global__ __launch_bounds__(256) void prep2_kernel(const bf16* __restrict__ x2b,
                                                    bf16* __restrict__ h,
                                                    const float* __restrict__ w1,
                                                    bf16* __restrict__ w1o, int n8) {
    if ((int)blockIdx.x < ROWS) rmsnorm_body_b16(x2b, h, blockIdx.x);
    else f2b_body(w1, w1o, (blockIdx.x - ROWS) * 256 + threadIdx.x, n8);
}

// conv4 (blocks [0,4096)) + f2b W_out ([4096,8192)) + f2b W_mlp2 ([8192,16384))
__global__ __launch_bounds__(256) void convf2b_kernel(bf16* __restrict__ xz,
                                                      const float* __restrict__ cw,
                                                      const float* __restrict__ cb,
                                                      const float* __restrict__ wo,
                                                      bf16* __restrict__ woOut,
                                                      const float* __restrict__ w2,
                                                      bf16* __restrict__ w2Out) {
    if ((int)blockIdx.x < 4096)
        conv4_body(xz, cw, cb, blockIdx.x * 256 + threadIdx.x);
    else if ((int)blockIdx.x < 8192)
        f2b_body(wo, woOut, (blockIdx.x - 4096) * 256 + threadIdx.x, 1048576);
    else
        f2b_body(w2, w2Out, (blockIdx.x - 8192) * 256 + threadIdx.x, 2097152);
}

// ---------------- bf16 GEMM v11 (proven best): C = A @ B^T ------------------
// 256x256 tile, BK=64, 512 threads = 8 waves (2M x 4N), per-wave 128x64.
// 2 dbuf x 64KB, XOR chunk swizzle (inverse-swizzled global source, 0
// conflicts), 2 super-phases/K-tile with refills under MFMA, counted
// vmcnt(4)/K-tile (FIFO B0,B1,A0,A1 -> retires exactly tile t+1), T5
// setprio, bijective 2D XCD map (gx==32: 4x2 XCD regions).
// EPI: 0 = bf16, 1 = relu+bf16, 2 = fp32-res add -> bf16 out,
//      3 = bf16-res add -> fp32 out
template<int EPI>
__global__ __launch_bounds__(512, 2) void gemm_bt(
        const bf16* __restrict__ A, long lda,
        const bf16* __restrict__ B,
        void* __restrict__ C, const void* __restrict__ res,
        int N, int K, int gx) {
    __shared__ __align__(16) char LB[131072];
    const int tid = threadIdx.x;
    const int w   = tid >> 6;
    const int l   = tid & 63;
    const int lr  = l & 15;

    int bx, by;
    if (gx == 32) {
        const int xcd = blockIdx.x & 7, i = blockIdx.x >> 3;
        by = (xcd >> 1) * 8 + (i >> 4);
        bx = (xcd & 1) * 16 + (i & 15);
    } else {
        const int qq = gridDim.x >> 3;
        const int sw = (blockIdx.x & 7) * qq + (blockIdx.x >> 3);
        bx = sw % gx; by = sw / gx;
    }
    const long rowBase = (long)by * 256;
    const long colBase = (long)bx * 256;

    const int srow = w * 8 + (l >> 3);
    const int schk = (l & 7) ^ ((l >> 3) & 7);
    const bf16* aSrc = A + (rowBase + srow) * lda + schk * 8;
    const bf16* bSrc = B + (colBase + srow) * (long)K + schk * 8;
    const long lda64 = 64 * lda;
    const long ldb64 = 64 * (long)K;
    const int  w1024 = w * 1024;

    auto stgA0 = [&](int DBB, int kt) {
        const bf16* s = aSrc + (long)kt * 64;
        gload_lds16(s,            LB + DBB +     0 + w1024);
        gload_lds16(s +   lda64,  LB + DBB +  8192 + w1024);
    };
    auto stgA1 = [&](int DBB, int kt) {
        const bf16* s = aSrc + (long)kt * 64;
        gload_lds16(s + 2*lda64,  LB + DBB + 16384 + w1024);
        gload_lds16(s + 3*lda64,  LB + DBB + 24576 + w1024);
    };
    auto stgB0 = [&](int DBB, int kt) {
        const bf16* s = bSrc + (long)kt * 64;
        gload_lds16(s,            LB + DBB + 32768 + w1024);
        gload_lds16(s +   ldb64,  LB + DBB + 40960 + w1024);
    };
    auto stgB1 = [&](int DBB, int kt) {
        const bf16* s = bSrc + (long)kt * 64;
        gload_lds16(s + 2*ldb64,  LB + DBB + 49152 + w1024);
        gload_lds16(s + 3*ldb64,  LB + DBB + 57344 + w1024);
    };

    const int cx0 = (((l >> 4)    ) ^ (l & 7)) << 4;
    const int cx1 = (((l >> 4) + 4) ^ (l & 7)) << 4;
    const int hm = w >> 2;
    const int q  = w & 3;
    int aRow[8], bRow[4];
    #pragma unroll
    for (int m = 0; m < 8; ++m) aRow[m] = hm * 16384 + (m * 16 + lr) * 128;
    #pragma unroll
    for (int n = 0; n < 4; ++n)
        bRow[n] = 32768 + (q >> 1) * 16384 + ((q & 1) * 64 + n * 16 + lr) * 128;

    const int nt  = K >> 6;
    const int nit = nt >> 1;
    f32x4 acc[8][4] = {};
    bf16x8 AX[4][2], BL[2][2], BH[2][2];

    stgB0(0, 0); stgB1(0, 0); stgA0(0, 0); stgA1(0, 0);
    stgB0(65536, 1); stgB1(65536, 1); stgA0(65536, 1); stgA1(65536, 1);
    asm volatile("s_waitcnt vmcnt(8)" ::: "memory");
    __builtin_amdgcn_s_barrier();
    __builtin_amdgcn_sched_barrier(0);
    #pragma unroll
    for (int m = 0; m < 4; ++m) {
        AX[m][0] = *(const bf16x8*)(LB + aRow[m] + cx0);
        AX[m][1] = *(const bf16x8*)(LB + aRow[m] + cx1);
    }
    #pragma unroll
    for (int n = 0; n < 2; ++n) {
        BL[n][0] = *(const bf16x8*)(LB + bRow[n]     + cx0);
        BL[n][1] = *(const bf16x8*)(LB + bRow[n]     + cx1);
    }
    #pragma unroll
    for (int n = 0; n < 2; ++n) {
        BH[n][0] = *(const bf16x8*)(LB + bRow[n + 2] + cx0);
        BH[n][1] = *(const bf16x8*)(LB + bRow[n + 2] + cx1);
    }
    asm volatile("s_waitcnt lgkmcnt(4)" ::: "memory");
    __builtin_amdgcn_sched_barrier(0);
    __builtin_amdgcn_s_setprio(1);
    #pragma unroll
    for (int m = 0; m < 4; ++m)
        #pragma unroll
        for (int n = 0; n < 2; ++n) {
            acc[m][n] = __builtin_amdgcn_mfma_f32_16x16x32_bf16(AX[m][0], BL[n][0], acc[m][n], 0, 0, 0);
            acc[m][n] = __builtin_amdgcn_mfma_f32_16x16x32_bf16(AX[m][1], BL[n][1], acc[m][n], 0, 0, 0);
        }
    __builtin_amdgcn_s_setprio(0);
    __builtin_amdgcn_s_barrier();

    for (int it = 0; it < nit; ++it) {
        int kA = 2 * it + 2; if (kA >= nt) kA = 0;
        int kB = 2 * it + 3; if (kB >= nt) kB = 0;
        #pragma unroll
        for (int db = 0; db < 2; ++db) {
            const int DBB = db * 65536;
            const char* Lb = LB + DBB;
            const char* Ln = LB + (DBB ^ 65536);
            const int kst = db ? kB : kA;
            const bool full = (db == 0) || (it < nit - 1);

            // ================= P_A =================
            stgB0(DBB, kst);
            __builtin_amdgcn_s_setprio(1);
            #pragma unroll
            for (int m = 0; m < 4; ++m) {                     // q2: A0 x BH
                #pragma unroll
                for (int n = 0; n < 2; ++n) {
                    acc[m][n + 2] = __builtin_amdgcn_mfma_f32_16x16x32_bf16(AX[m][0], BH[n][0], acc[m][n + 2], 0, 0, 0);
                    acc[m][n + 2] = __builtin_amdgcn_mfma_f32_16x16x32_bf16(AX[m][1], BH[n][1], acc[m][n + 2], 0, 0, 0);
                }
                AX[m][0] = *(const bf16x8*)(Lb + aRow[m + 4] + cx0);
                AX[m][1] = *(const bf16x8*)(Lb + aRow[m + 4] + cx1);
            }
            __builtin_amdgcn_s_setprio(0);
            stgB1(DBB, kst);
            asm volatile("s_waitcnt lgkmcnt(0)" ::: "memory");
            __builtin_amdgcn_sched_barrier(0);
            __builtin_amdgcn_s_setprio(1);
            #pragma unroll
            for (int m = 0; m < 4; ++m)                       // q3: A1 x BH
                #pragma unroll
                for (int n = 0; n < 2; ++n) {
                    acc[m + 4][n + 2] = __builtin_amdgcn_mfma_f32_16x16x32_bf16(AX[m][0], BH[n][0], acc[m + 4][n + 2], 0, 0, 0);
                    acc[m + 4][n + 2] = __builtin_amdgcn_mfma_f32_16x16x32_bf16(AX[m][1], BH[n][1], acc[m + 4][n + 2], 0, 0, 0);
                }
            __builtin_amdgcn_s_setprio(0);
            asm volatile("s_waitcnt vmcnt(4)" ::: "memory");  // t+1 landed (FIFO)
            __builtin_amdgcn_s_barrier();
            __builtin_amdgcn_sched_barrier(0);

            // ================= P_B =================
            __builtin_amdgcn_s_setprio(1);
            #pragma unroll
            for (int m = 0; m < 4; ++m) {                     // q4: A1 x BL
                #pragma unroll
                for (int n = 0; n < 2; ++n) {
                    acc[m + 4][n] = __builtin_amdgcn_mfma_f32_16x16x32_bf16(AX[m][0], BL[n][0], acc[m + 4][n], 0, 0, 0);
                    acc[m + 4][n] = __builtin_amdgcn_mfma_f32_16x16x32_bf16(AX[m][1], BL[n][1], acc[m + 4][n], 0, 0, 0);
                }
                if (full) {
                    AX[m][0] = *(const bf16x8*)(Ln + aRow[m] + cx0);
                    AX[m][1] = *(const bf16x8*)(Ln + aRow[m] + cx1);
                    if (m < 2) {                               // BH refill under q4
                        BH[m][0] = *(const bf16x8*)(Ln + bRow[m + 2] + cx0);
                        BH[m][1] = *(const bf16x8*)(Ln + bRow[m + 2] + cx1);
                    }
                }
            }
            __builtin_amdgcn_s_setprio(0);
            __builtin_amdgcn_sched_barrier(0);
            stgA0(DBB, kst);
            if (full) {
                #pragma unroll
                for (int n = 0; n < 2; ++n) {                  // BL <- B0(t+1)
                    BL[n][0] = *(const bf16x8*)(Ln + bRow[n]     + cx0);
                    BL[n][1] = *(const bf16x8*)(Ln + bRow[n]     + cx1);
                }
            }
            stgA1(DBB, kst);
            if (full) {
                asm volatile("s_waitcnt lgkmcnt(0)" ::: "memory");
                __builtin_amdgcn_sched_barrier(0);
                __builtin_amdgcn_s_setprio(1);
                #pragma unroll
                for (int m = 0; m < 4; ++m)                   // q1(t+1): A0 x B0
                    #pragma unroll
                    for (int n = 0; n < 2; ++n) {
                        acc[m][n] = __builtin_amdgcn_mfma_f32_16x16x32_bf16(AX[m][0], BL[n][0], acc[m][n], 0, 0, 0);
                        acc[m][n] = __builtin_amdgcn_mfma_f32_16x16x32_bf16(AX[m][1], BL[n][1], acc[m][n], 0, 0, 0);
                    }
                __builtin_amdgcn_s_setprio(0);
            }
            __builtin_amdgcn_s_barrier();
        }
    }

    asm volatile("s_waitcnt vmcnt(0)" ::: "memory");
    __builtin_amdgcn_s_barrier();

    // epilogue
    const int lg = l >> 4;
    const long wrow = rowBase + hm * 128;
    const long wcol = colBase + q * 64;
    char* ep = LB + w * 16384;

    if (EPI == 3) {
        // bf16 res add -> fp32 out, two 64-row passes via fp32 LDS
        const bf16* rb = (const bf16*)res;
        #pragma unroll
        for (int mh = 0; mh < 2; ++mh) {
            #pragma unroll
            for (int m = 0; m < 4; ++m) {
                #pragma unroll
                for (int n = 0; n < 4; ++n) {
                    f32x4 v = acc[mh * 4 + m][n];
                    #pragma unroll
                    for (int r = 0; r < 4; ++r) {
                        int rowr = m * 16 + lg * 4 + r;
                        int chnk = (n * 4 + (lr >> 2)) ^ (rowr & 7);
                        *(float*)(ep + rowr * 256 + chnk * 16 + (lr & 3) * 4) = v[r];
                    }
                }
            }
            asm volatile("s_waitcnt lgkmcnt(0)" ::: "memory");
            #pragma unroll
            for (int i = 0; i < 16; ++i) {
                int rr = i * 4 + (l >> 4);
                float4 lv = *(float4*)(ep + rr * 256 + (((l & 15) ^ (rr & 7)) * 16));
                long off = (wrow + mh * 64 + rr) * N + wcol + (l & 15) * 4;
                bf16x4 rv = *(const bf16x4*)(rb + off);
                lv.x += (float)rv[0]; lv.y += (float)rv[1];
                lv.z += (float)rv[2]; lv.w += (float)rv[3];
                *(float4*)((float*)C + off) = lv;
            }
            if (mh == 0) { asm volatile("s_waitcnt lgkmcnt(0) vmcnt(0)" ::: "memory"); }
        }
    } else {
        // bf16 out (EPI 0/1/2), single pass [128][64] bf16 LDS
        const float* rf = (const float*)res;
        #pragma unroll
        for (int m = 0; m < 8; ++m) {
            #pragma unroll
            for (int n = 0; n < 4; ++n) {
                f32x4 v = acc[m][n];
                #pragma unroll
                for (int r = 0; r < 4; ++r) {
                    int rowr = m * 16 + lg * 4 + r;
                    int chnk = (n * 2 + (lr >> 3)) ^ (rowr & 7);
                    float val = v[r];
                    if (EPI == 1) val = fmaxf(val, 0.f);
                    if (EPI == 2) val += rf[(wrow + rowr) * N + wcol + n * 16 + lr];
                    *(bf16*)(ep + rowr * 128 + chnk * 16 + (lr & 7) * 2) = (bf16)val;
                }
            }
        }
        asm volatile("s_waitcnt lgkmcnt(0)" ::: "memory");
        #pragma unroll
        for (int i = 0; i < 16; ++i) {
            int rr = i * 8 + (l >> 3);
            uint4 lv = *(uint4*)(ep + rr * 128 + (((l & 7) ^ (rr & 7)) * 16));
            *(uint4*)((bf16*)C + (wrow + rr) * N + wcol + (l & 7) * 8) = lv;
        }
    }
}

extern "C" void kernel_launch(void* const* d_in, const int* in_sizes, int n_in,
                              void* d_out, int out_size, void* d_ws, size_t ws_size,
                              hipStream_t stream) {
    const float* x      = (const float*)d_in[0];
    const float* W_in   = (const float*)d_in[1];
    const float* cw     = (const float*)d_in[2];
    const float* cb     = (const float*)d_in[3];
    const float* W_out  = (const float*)d_in[4];
    const float* W_mlp1 = (const float*)d_in[5];
    const float* W_mlp2 = (const float*)d_in[6];
    float* out = (float*)d_out;

    char* ws  = (char*)d_ws;
    bf16* wW  = (bf16*)(ws);                    // 33.55 MB
    bf16* h   = (bf16*)(ws + 33554432);         // 33.55 MB
    bf16* xz  = (bf16*)(ws + 67108864);         // 134.2 MB (xz / m1)
    bf16* x2b = (bf16*)(ws + 201326592);        // 33.55 MB (bf16 residual)
    bf16* wW2 = (bf16*)(ws + 234881024);        // 33.55 MB (W_mlp2 bf16)
    bf16* y   = xz + D_INNER;                   // z-half in place, lda = 8192
    bf16* m1  = xz;

    dim3 blk(256);
    dim3 gblk(512);

    // mamba branch
    prep_kernel<<<dim3(ROWS + 8192), blk, 0, stream>>>(x, h, W_in, wW, 16777216/8);
    gemm_bt<0><<<dim3(1024), gblk, 0, stream>>>(h, D_MODEL, wW, xz, nullptr, 2*D_INNER, D_MODEL, 32);
    convf2b_kernel<<<dim3(16384), blk, 0, stream>>>(xz, cw, cb, W_out, wW, W_mlp2, wW2);
    gemm_bt<2><<<dim3(256), gblk, 0, stream>>>(y, 2*D_INNER, wW, x2b, x, D_MODEL, D_INNER, 8);

    // mlp branch
    prep2_kernel<<<dim3(2 * ROWS), blk, 0, stream>>>(x2b, h, W_mlp1, wW, 16777216/8);
    gemm_bt<1><<<dim3(1024), gblk, 0, stream>>>(h, D_MODEL, wW, m1, nullptr, 4*D_MODEL, D_MODEL, 32);
    gemm_bt<3><<<dim3(256), gblk, 0, stream>>>(m1, 4*D_MODEL, wW2, out, x2b, D_MODEL, 4*D_MODEL, 8);
}